// Round 1
// baseline (236.503 us; speedup 1.0000x reference)
//
#include <hip/hip_runtime.h>
#include <hip/hip_cooperative_groups.h>
#include <math.h>

namespace cg = cooperative_groups;

#define NN 1024      // N
#define DIN 512      // D_IN
#define DD 128       // D
#define NSPLIT 8     // split-K factor (32 rowblocks x 8 splits = 256 blocks)

static constexpr long S = (long)NN * DD;       // 131072 floats per matrix
// ws layout (floats)
static constexpr long XP_OFF = 0;                      // 8 x-partials
static constexpr long ZP_OFF = XP_OFF + NSPLIT * S;    // 8 z-partials
static constexpr long X_OFF  = ZP_OFF + NSPLIT * S;
static constexpr long Z_OFF  = X_OFF + S;
static constexpr long U_OFF  = Z_OFF + S;
static constexpr long A_OFF  = U_OFF + 256;
static constexpr long B_OFF  = A_OFF + NN;

// ---------------------------------------------------------------------------
// Split-K fp32 GEMM partial (verified body from the 5-kernel version).
// bid encodes (rowblock = bid&31, split = bid>>5). 32 rows x 128 cols per
// block, 16 independent accumulators per thread.
__device__ __forceinline__ void gemm_part_dev(
    const float* __restrict__ A, const float* __restrict__ B,
    float* __restrict__ Cp, int K, int Kc, int bid, int t) {
  const int tx = t & 31;
  const int ty = t >> 5;
  const int row0 = (bid & 31) * 32;
  const int k0 = (bid >> 5) * Kc;

  float acc[4][4] = {};

  for (int k = k0; k < k0 + Kc; k += 4) {
    float bv[4][4];
#pragma unroll
    for (int kk = 0; kk < 4; ++kk) {
      const float* Brow = &B[(long)(k + kk) * DD + tx];
#pragma unroll
      for (int mc = 0; mc < 4; ++mc) bv[kk][mc] = Brow[32 * mc];
    }
#pragma unroll
    for (int mr = 0; mr < 4; ++mr) {
      const int r = row0 + ty + 8 * mr;
      const float4 av = *(const float4*)&A[(long)r * K + k];
      const float ar[4] = {av.x, av.y, av.z, av.w};
#pragma unroll
      for (int kk = 0; kk < 4; ++kk)
#pragma unroll
        for (int mc = 0; mc < 4; ++mc) acc[mr][mc] += ar[kk] * bv[kk][mc];
    }
  }

  float* Cs = Cp + (long)(bid >> 5) * S;
#pragma unroll
  for (int mr = 0; mr < 4; ++mr) {
    const int r = row0 + ty + 8 * mr;
#pragma unroll
    for (int mc = 0; mc < 4; ++mc)
      Cs[(long)r * DD + tx + 32 * mc] = acc[mr][mc];
  }
}

// ---------------------------------------------------------------------------
// One cooperative kernel: 256 blocks x 256 threads, 4 grid syncs.
// Replaces 5 serial dispatches (launch/drain overhead was ~85 of 109 us).
__global__ __launch_bounds__(256) void fused(
    const float* __restrict__ inputs, const float* __restrict__ adj,
    const float* __restrict__ weight, const float* __restrict__ W2,
    const float* __restrict__ w3, float* __restrict__ out,
    float* __restrict__ ws) {
  cg::grid_group grid = cg::this_grid();
  __shared__ float zwl[64 * DD];  // 32 KB, used only by the decode stage

  const int t = threadIdx.x;
  const int bid = blockIdx.x;

  float* xp = ws + XP_OFF;
  float* zp = ws + ZP_OFF;
  float* x  = ws + X_OFF;
  float* z  = ws + Z_OFF;
  float* u  = ws + U_OFF;
  float* a  = ws + A_OFF;
  float* b  = ws + B_OFF;

  // ---- S1a: x partials (inputs @ weight, split-K 8, Kc = 64) -------------
  gemm_part_dev(inputs, weight, xp, DIN, DIN / NSPLIT, bid, t);
  grid.sync();

  // ---- S1b: reduce 8 x-partials -> x ; u[bid] = (W2 @ w3[:128])[bid] -----
  {
    const long i0 = (long)bid * 512;
    float s0 = 0.f, s1 = 0.f;
#pragma unroll
    for (int p = 0; p < NSPLIT; ++p) {
      s0 += xp[p * S + i0 + t];
      s1 += xp[p * S + i0 + 256 + t];
    }
    x[i0 + t] = s0;
    x[i0 + 256 + t] = s1;

    if (t < 64) {  // wave 0: u[bid], 2 products/lane + 64-lane shfl reduce
      float p = W2[(long)bid * DD + t] * w3[t] +
                W2[(long)bid * DD + 64 + t] * w3[64 + t];
#pragma unroll
      for (int off = 32; off > 0; off >>= 1) p += __shfl_down(p, off);
      if (t == 0) u[bid] = p;
    }
  }
  grid.sync();

  // ---- S2a: z partials (adj @ x, split-K 8, Kc = 128) --------------------
  gemm_part_dev(adj, x, zp, NN, NN / NSPLIT, bid, t);
  grid.sync();

  // ---- S2b: reduce 8 z-partials -> z ; fused a_i / b_i -------------------
  // One wave per row: rows 4*bid .. 4*bid+3, lane handles cols 2l, 2l+1.
  {
    const int w = t >> 6;
    const int l = t & 63;
    const int i = 4 * bid + w;
    const long base = (long)i * DD + 2 * l;
    float s0 = 0.f, s1 = 0.f;
#pragma unroll
    for (int p = 0; p < NSPLIT; ++p) {
      const float2 v = *(const float2*)&zp[p * S + base];
      s0 += v.x; s1 += v.y;
    }
    *(float2*)&z[base] = make_float2(s0, s1);

    const float r0 = s0 > 0.f ? s0 : 0.f;
    const float r1 = s1 > 0.f ? s1 : 0.f;
    float pa = r0 * u[2 * l] + r1 * u[2 * l + 1];
    float pb = r0 * u[DD + 2 * l] + r1 * u[DD + 2 * l + 1];
#pragma unroll
    for (int off = 32; off > 0; off >>= 1) {
      pa += __shfl_down(pa, off);
      pb += __shfl_down(pb, off);
    }
    if (l == 0) { a[i] = pa; b[i] = pb; }
  }
  grid.sync();

  // ---- S3: decode (verified hybrid LDS/L1 body, 64x64 tile per block) ----
  {
    const int i0 = (bid >> 4) * 64;
    const int j0 = (bid & 15) * 64;

#pragma unroll
    for (int s = 0; s < 8; ++s) {
      const int q = s * 256 + t;
      const int r = q >> 5;
      const int k4 = (q & 31) << 2;
      float4 wv = *(const float4*)&z[(long)(j0 + r) * DD + k4];
      const float4 cc = *(const float4*)&w3[DD + k4];
      wv.x *= cc.x; wv.y *= cc.y; wv.z *= cc.z; wv.w *= cc.w;
      *(float4*)&zwl[r * DD + (k4 ^ ((r & 7) << 2))] = wv;
    }
    __syncthreads();

    const int tx = t & 15;
    const int ty = t >> 4;
    float acc[4][4] = {};
    for (int k4 = 0; k4 < DD; k4 += 4) {
      float4 ar[4], bc[4];
#pragma unroll
      for (int m = 0; m < 4; ++m)  // i-side from global (L1-resident)
        ar[m] = *(const float4*)&z[(long)(i0 + ty + 16 * m) * DD + k4];
#pragma unroll
      for (int m = 0; m < 4; ++m) {
        const int C = tx + 16 * m;
        bc[m] = *(const float4*)&zwl[C * DD + (k4 ^ ((C & 7) << 2))];
      }
#pragma unroll
      for (int mr = 0; mr < 4; ++mr)
#pragma unroll
        for (int mc = 0; mc < 4; ++mc)
          acc[mr][mc] += ar[mr].x * bc[mc].x + ar[mr].y * bc[mc].y +
                         ar[mr].z * bc[mc].z + ar[mr].w * bc[mc].w;
    }

#pragma unroll
    for (int mr = 0; mr < 4; ++mr) {
      const int i = i0 + ty + 16 * mr;
      const float ai = a[i];
#pragma unroll
      for (int mc = 0; mc < 4; ++mc) {
        const int j = j0 + tx + 16 * mc;
        const float sc = ai + b[j] + acc[mr][mc];
        out[(long)i * NN + j] = 1.0f / (1.0f + __expf(-sc));
      }
    }
  }
}

// ---------------------------------------------------------------------------
extern "C" void kernel_launch(void* const* d_in, const int* in_sizes, int n_in,
                              void* d_out, int out_size, void* d_ws, size_t ws_size,
                              hipStream_t stream) {
  (void)in_sizes; (void)n_in; (void)out_size; (void)ws_size;
  const float* inputs = (const float*)d_in[0];   // (1024, 512)
  const float* adj    = (const float*)d_in[1];   // (1024, 1024)
  const float* weight = (const float*)d_in[2];   // (512, 128)
  const float* W2     = (const float*)d_in[3];   // (256, 128)
  const float* w3     = (const float*)d_in[4];   // (256,)
  float* out = (float*)d_out;
  float* ws  = (float*)d_ws;

  void* args[] = {(void*)&inputs, (void*)&adj, (void*)&weight, (void*)&W2,
                  (void*)&w3, (void*)&out, (void*)&ws};
  hipLaunchCooperativeKernel((const void*)fused, dim3(256), dim3(256), args,
                             0, stream);
}

// Round 3
// 109.331 us; speedup vs baseline: 2.1632x; 2.1632x over previous
//
#include <hip/hip_runtime.h>
#include <math.h>

#define NN 1024      // N
#define DIN 512      // D_IN
#define DD 128       // D
#define NSPLIT 8     // split-K factor

static constexpr long S = (long)NN * DD;       // 131072 floats per matrix
// ws layout (floats)
static constexpr long XP_OFF = 0;                      // 8 x-partials
static constexpr long ZP_OFF = XP_OFF + NSPLIT * S;    // 8 z-partials
static constexpr long X_OFF  = ZP_OFF + NSPLIT * S;
static constexpr long Z_OFF  = X_OFF + S;
static constexpr long U_OFF  = Z_OFF + S;
static constexpr long A_OFF  = U_OFF + 256;
static constexpr long B_OFF  = A_OFF + NN;

// ---------------------------------------------------------------------------
// Split-K fp32 GEMM partial: 16 rows x 128 cols per block.
// grid = (64 rowblocks, NSPLIT splits [+1 extra row for the u-block]).
// Thread (tx=t&31, ty=t>>5): rows ty+8*mr (mr<2), cols 4*tx+mc (mc<4).
// B loads are float4 (4 per k4-step instead of 16 scalars); C-stores float4.
__global__ __launch_bounds__(256) void gemm16(
    const float* __restrict__ A, const float* __restrict__ B,
    float* __restrict__ Cp, int K, int Kc,
    const float* __restrict__ W2, const float* __restrict__ w3,
    float* __restrict__ u) {
  if (blockIdx.y == NSPLIT) {  // u-block: u = (W2 @ w3[:128]), 256 entries
    if (blockIdx.x == 0) {
      const int kq = threadIdx.x;  // 0..255
      const float4* Wr = (const float4*)&W2[(long)kq * DD];
      float uu = 0.f;
#pragma unroll 8
      for (int l = 0; l < DD / 4; ++l) {
        const float4 wv = Wr[l];
        const float4 cv = ((const float4*)w3)[l];
        uu += wv.x * cv.x + wv.y * cv.y + wv.z * cv.z + wv.w * cv.w;
      }
      u[kq] = uu;
    }
    return;
  }

  const int t = threadIdx.x;
  const int tx = t & 31;
  const int ty = t >> 5;               // 0..7
  const int row0 = blockIdx.x * 16;
  const int k0 = blockIdx.y * Kc;

  float acc[2][4] = {};

  for (int k = k0; k < k0 + Kc; k += 4) {
    float4 bv[4];
#pragma unroll
    for (int kk = 0; kk < 4; ++kk)
      bv[kk] = *(const float4*)&B[(long)(k + kk) * DD + 4 * tx];
    float4 av[2];
#pragma unroll
    for (int mr = 0; mr < 2; ++mr)
      av[mr] = *(const float4*)&A[(long)(row0 + ty + 8 * mr) * K + k];
#pragma unroll
    for (int mr = 0; mr < 2; ++mr) {
      const float ar[4] = {av[mr].x, av[mr].y, av[mr].z, av[mr].w};
#pragma unroll
      for (int kk = 0; kk < 4; ++kk) {
        acc[mr][0] += ar[kk] * bv[kk].x;
        acc[mr][1] += ar[kk] * bv[kk].y;
        acc[mr][2] += ar[kk] * bv[kk].z;
        acc[mr][3] += ar[kk] * bv[kk].w;
      }
    }
  }

  float* Cs = Cp + (long)blockIdx.y * S;
#pragma unroll
  for (int mr = 0; mr < 2; ++mr) {
    const int r = row0 + ty + 8 * mr;
    *(float4*)&Cs[(long)r * DD + 4 * tx] =
        make_float4(acc[mr][0], acc[mr][1], acc[mr][2], acc[mr][3]);
  }
}

// ---------------------------------------------------------------------------
// Reduce 8 x-partials -> x. Pure reduce (u moved into gemm16's spare block).
__global__ __launch_bounds__(256) void reduce_x(
    const float* __restrict__ xp, float* __restrict__ x) {
  const long i = (long)blockIdx.x * 256 + threadIdx.x;  // 0..131071
  float s = 0.f;
#pragma unroll
  for (int p = 0; p < NSPLIT; ++p) s += xp[p * S + i];
  x[i] = s;
}

// ---------------------------------------------------------------------------
// Reduce 8 z-partials -> z ; fused a_i/b_i. grid = 1024 rows, block = 128.
__global__ __launch_bounds__(128) void finalize_z(
    const float* __restrict__ zp, float* __restrict__ z,
    const float* __restrict__ u, float* __restrict__ a, float* __restrict__ b) {
  __shared__ float red[2][2];
  const int i = blockIdx.x;
  const int c = threadIdx.x;  // 0..127 = column
  float s = 0.f;
#pragma unroll
  for (int p = 0; p < NSPLIT; ++p) s += zp[p * S + (long)i * DD + c];
  z[(long)i * DD + c] = s;

  const float r = s > 0.f ? s : 0.f;
  float pa = r * u[c];
  float pb = r * u[DD + c];
#pragma unroll
  for (int off = 32; off > 0; off >>= 1) {
    pa += __shfl_down(pa, off);
    pb += __shfl_down(pb, off);
  }
  const int w = c >> 6;
  if ((c & 63) == 0) { red[w][0] = pa; red[w][1] = pb; }
  __syncthreads();
  if (c == 0) {
    a[i] = red[0][0] + red[1][0];
    b[i] = red[0][1] + red[1][1];
  }
}

// ---------------------------------------------------------------------------
// Decode: out[i,j] = sigmoid(a[i]+b[j]+z_i.(z_j*w3[128:])). 32x64 tile,
// 512 blocks (2/CU, 8 waves/CU). j-side (scaled) in LDS (32 KB, XOR-swizzled
// -> conflict-free b128 reads); i-side from global z (L1-resident).
__global__ __launch_bounds__(256) void k4_decode(
    const float* __restrict__ z, const float* __restrict__ w3,
    const float* __restrict__ a, const float* __restrict__ b,
    float* __restrict__ out) {
  __shared__ float zwl[64 * DD];
  const int t = threadIdx.x;
  const int i0 = blockIdx.y * 32;
  const int j0 = blockIdx.x * 64;

#pragma unroll
  for (int s = 0; s < 8; ++s) {
    const int q = s * 256 + t;
    const int r = q >> 5;            // 0..63 (j-row within tile)
    const int k4 = (q & 31) << 2;
    float4 w = *(const float4*)&z[(long)(j0 + r) * DD + k4];
    const float4 cc = *(const float4*)&w3[DD + k4];
    w.x *= cc.x; w.y *= cc.y; w.z *= cc.z; w.w *= cc.w;
    *(float4*)&zwl[r * DD + (k4 ^ ((r & 7) << 2))] = w;
  }
  __syncthreads();

  const int tx = t & 15;
  const int ty = t >> 4;             // 0..15
  float acc[2][4] = {};
  for (int k4 = 0; k4 < DD; k4 += 4) {
    float4 ar[2], bc[4];
#pragma unroll
    for (int m = 0; m < 2; ++m)      // i-side from global (L1-resident)
      ar[m] = *(const float4*)&z[(long)(i0 + ty + 16 * m) * DD + k4];
#pragma unroll
    for (int m = 0; m < 4; ++m) {
      const int C = tx + 16 * m;
      bc[m] = *(const float4*)&zwl[C * DD + (k4 ^ ((C & 7) << 2))];
    }
#pragma unroll
    for (int mr = 0; mr < 2; ++mr)
#pragma unroll
      for (int mc = 0; mc < 4; ++mc)
        acc[mr][mc] += ar[mr].x * bc[mc].x + ar[mr].y * bc[mc].y +
                       ar[mr].z * bc[mc].z + ar[mr].w * bc[mc].w;
  }

#pragma unroll
  for (int mr = 0; mr < 2; ++mr) {
    const int i = i0 + ty + 16 * mr;
    const float ai = a[i];
#pragma unroll
    for (int mc = 0; mc < 4; ++mc) {
      const int j = j0 + tx + 16 * mc;
      const float sc = ai + b[j] + acc[mr][mc];
      out[(long)i * NN + j] = 1.0f / (1.0f + __expf(-sc));
    }
  }
}

// ---------------------------------------------------------------------------
extern "C" void kernel_launch(void* const* d_in, const int* in_sizes, int n_in,
                              void* d_out, int out_size, void* d_ws, size_t ws_size,
                              hipStream_t stream) {
  (void)in_sizes; (void)n_in; (void)out_size; (void)ws_size;
  const float* inputs = (const float*)d_in[0];   // (1024, 512)
  const float* adj    = (const float*)d_in[1];   // (1024, 1024)
  const float* weight = (const float*)d_in[2];   // (512, 128)
  const float* W2     = (const float*)d_in[3];   // (256, 128)
  const float* w3     = (const float*)d_in[4];   // (256,)
  float* out = (float*)d_out;

  float* ws = (float*)d_ws;
  float* xp = ws + XP_OFF;
  float* zp = ws + ZP_OFF;
  float* x  = ws + X_OFF;
  float* z  = ws + Z_OFF;
  float* u  = ws + U_OFF;
  float* a  = ws + A_OFF;
  float* b  = ws + B_OFF;

  // 1) x partials (split-K 8, Kc=64) + u in spare block row
  gemm16<<<dim3(64, NSPLIT + 1), 256, 0, stream>>>(inputs, weight, xp, DIN,
                                                   DIN / NSPLIT, W2, w3, u);
  // 2) reduce x
  reduce_x<<<512, 256, 0, stream>>>(xp, x);
  // 3) z partials (split-K 8, Kc=128)
  gemm16<<<dim3(64, NSPLIT), 256, 0, stream>>>(adj, x, zp, NN, NN / NSPLIT,
                                               W2, w3, u);
  // 4) reduce z + a,b
  finalize_z<<<1024, 128, 0, stream>>>(zp, z, u, a, b);
  // 5) decode (32x64 tiles, 2 blocks/CU)
  k4_decode<<<dim3(16, 32), 256, 0, stream>>>(z, w3, a, b, out);
}